// Round 6
// baseline (468.259 us; speedup 1.0000x reference)
//
#include <hip/hip_runtime.h>

#define B_ROWS 32768
#define T_BINS 1024

typedef __attribute__((ext_vector_type(8))) _Float16 half8;
typedef __attribute__((ext_vector_type(4))) _Float16 half4;
typedef __attribute__((ext_vector_type(4))) float floatx4;

__device__ __forceinline__ unsigned long long pack_max(float v, int col) {
    unsigned x = __float_as_uint(v);
    x = (x & 0x80000000u) ? ~x : (x | 0x80000000u);   // monotone float->uint
    return ((unsigned long long)x << 32) | (unsigned)(~col);  // ties -> smaller col
}

__device__ __forceinline__ void async16h(const _Float16* g, _Float16* l) {
    __builtin_amdgcn_global_load_lds(
        (const __attribute__((address_space(1))) unsigned int*)g,
        (__attribute__((address_space(3))) unsigned int*)l,
        16, 0, 0);
}

// ---------------- convert fp32 -> f16 (RNE), used for W only ----------------
__global__ __launch_bounds__(256) void tof16_kernel(
    const float* __restrict__ src, _Float16* __restrict__ dst, int n4)
{
    int idx = blockIdx.x * 256 + threadIdx.x;
    if (idx >= n4) return;
    float4 x = ((const float4*)src)[idx];
    union { _Float16 h[4]; ushort4 u; } cv;
    cv.h[0] = (_Float16)x.x;
    cv.h[1] = (_Float16)x.y;
    cv.h[2] = (_Float16)x.z;
    cv.h[3] = (_Float16)x.w;
    ((ushort4*)dst)[idx] = cv.u;
}

// ---------------- MEGA: GEMM+argmax (full row per block) + loss + scan ----------------
// M=32 rows per block -> grid 1024 = 4 blocks/CU (R4's grid of 512 = 2 blocks/CU was
// the latency bottleneck: all 8 resident waves hit each K-iter barrier in lockstep).
// bx=0..3 over 256-col slices keeps the full-row argmax block-local.
// A converted fp32->f16 in-register at staging; W pre-converted once (f16 in d_ws).
__global__ __launch_bounds__(256, 4) void mega_kernel(
    const float* __restrict__ A, const _Float16* __restrict__ Wh,
    const float* __restrict__ bias, const float* __restrict__ labels,
    float* __restrict__ out_trunc, float* __restrict__ out_S,
    float* __restrict__ loss_acc)
{
    __shared__ _Float16 sA[32 * 32];    // [row][k] halves, 64B row stride
    __shared__ _Float16 sW[256 * 32];
    __shared__ unsigned long long cand[4][32];
    __shared__ float trunc_s[32];

    const int tid  = threadIdx.x;
    const int lane = tid & 63;
    const int wc   = tid >> 6;      // wave = column group 0..3
    const int by   = blockIdx.x;    // row slab 0..1023

    // A staging: thread -> (row=tid>>3, kgroup=(tid&7)*4); float4 -> half4 -> ds_write_b64
    const int arow = tid >> 3;
    const int akg  = (tid & 7) * 4;
    const float* Abase = A + (size_t)(by * 32 + arow) * T_BINS + akg;
    _Float16* sAdst = &sA[arow * 32 + akg];

    const int ko = (lane >> 4) * 8;  // k-offset of this lane's fragment

    float run_best[2][4];
    int   run_col[2][4];
#pragma unroll
    for (int i = 0; i < 2; ++i)
#pragma unroll
        for (int r = 0; r < 4; ++r) { run_best[i][r] = -3.4e38f; run_col[i][r] = 0; }

    // prologue A prefetch (k=0); k-wrap makes the last prefetch of each bx
    // exactly the first tile of the next bx (A is bx-independent).
    float4 pa = *(const float4*)(Abase);

    for (int bx = 0; bx < 4; ++bx) {
        const int colbase = bx * 256 + wc * 64 + (lane & 15);
        float bj[4];
#pragma unroll
        for (int j = 0; j < 4; ++j) bj[j] = bias[colbase + j * 16];

        floatx4 acc[2][4];
#pragma unroll
        for (int i = 0; i < 2; ++i)
#pragma unroll
            for (int j = 0; j < 4; ++j) acc[i][j] = (floatx4){0.f, 0.f, 0.f, 0.f};

        for (int k0 = 0; k0 < T_BINS; k0 += 32) {
            // 1. convert prefetched A regs (RNE), write 8B to LDS
            half4 hv;
            hv[0] = (_Float16)pa.x; hv[1] = (_Float16)pa.y;
            hv[2] = (_Float16)pa.z; hv[3] = (_Float16)pa.w;
            *(half4*)sAdst = hv;                        // ds_write_b64, conflict-free
            // 2. async-stage W tile (256 rows x 32 k)
#pragma unroll
            for (int r = 0; r < 4; ++r) {
                int c = r * 256 + tid;
                int wrow = c >> 2, wkc = (c & 3) * 8;
                async16h(Wh + (size_t)(bx * 256 + wrow) * T_BINS + k0 + wkc,
                         &sW[(r * 256 + wc * 64) * 8]);
            }
            // 3. prefetch next A tile (wraps to k=0 at bx boundary)
            int kn = (k0 + 32) & (T_BINS - 1);
            pa = *(const float4*)(Abase + kn);
            // 4. drain staging, sync
            asm volatile("s_waitcnt vmcnt(0)" ::: "memory");
            __syncthreads();
            // 5. fragments + MFMA
            half8 ah[2], whf[4];
#pragma unroll
            for (int i = 0; i < 2; ++i)
                ah[i] = *(const half8*)&sA[(i * 16 + (lane & 15)) * 32 + ko];
#pragma unroll
            for (int j = 0; j < 4; ++j)
                whf[j] = *(const half8*)&sW[(wc * 64 + j * 16 + (lane & 15)) * 32 + ko];
#pragma unroll
            for (int i = 0; i < 2; ++i)
#pragma unroll
                for (int j = 0; j < 4; ++j)
                    acc[i][j] = __builtin_amdgcn_mfma_f32_16x16x32_f16(ah[i], whf[j], acc[i][j], 0, 0, 0);
            __syncthreads();
        }

        // fold this bx's acc into the running argmax (cols strictly increase)
#pragma unroll
        for (int i = 0; i < 2; ++i)
#pragma unroll
            for (int r = 0; r < 4; ++r)
#pragma unroll
                for (int j = 0; j < 4; ++j) {
                    float v = acc[i][j][r] + bj[j];
                    if (v > run_best[i][r]) { run_best[i][r] = v; run_col[i][r] = colbase + j * 16; }
                }
    }

    // 16-lane (column-lane) reduce; lanes {0,16,32,48} publish per-row candidates
#pragma unroll
    for (int i = 0; i < 2; ++i)
#pragma unroll
        for (int r = 0; r < 4; ++r) {
            float best = run_best[i][r];
            int   bc   = run_col[i][r];
#pragma unroll
            for (int off = 8; off >= 1; off >>= 1) {
                float ov = __shfl_xor(best, off, 64);
                int   oc = __shfl_xor(bc, off, 64);
                if (ov > best || (ov == best && oc < bc)) { best = ov; bc = oc; }
            }
            if ((lane & 15) == 0)
                cand[wc][i * 16 + (lane >> 4) * 4 + r] = pack_max(best, bc);
        }
    __syncthreads();

    // wave 0: combine 4 col-group candidates per row (32 rows), trunc_pos + loss
    if (tid < 64) {
        float term = 0.f;
        if (tid < 32) {
            unsigned long long m01 = cand[0][tid] > cand[1][tid] ? cand[0][tid] : cand[1][tid];
            unsigned long long m23 = cand[2][tid] > cand[3][tid] ? cand[2][tid] : cand[3][tid];
            unsigned long long mm = m01 > m23 ? m01 : m23;
            unsigned col = ~(unsigned)mm;
            float p = (float)col;
            int rowG = by * 32 + tid;
            out_trunc[rowG] = p;
            trunc_s[tid] = p;
            float d = p - labels[rowG];
            term = d * d * (1.0f / (float)B_ROWS);
        }
#pragma unroll
        for (int off = 32; off >= 1; off >>= 1)
            term += __shfl_down(term, off, 64);
        if (tid == 0) atomicAdd(loss_acc, term);
    }
    __syncthreads();

    // scan phase: wave wc handles rows wc*8 .. wc*8+7; lane covers 16 elements
    for (int rr = 0; rr < 8; ++rr) {
        int row  = wc * 8 + rr;
        int rowG = by * 32 + row;
        const float* Hrow = A + (size_t)rowG * T_BINS + lane * 16;
        float4 h0 = *(const float4*)(Hrow + 0);
        float4 h1 = *(const float4*)(Hrow + 4);
        float4 h2 = *(const float4*)(Hrow + 8);
        float4 h3 = *(const float4*)(Hrow + 12);
        float hv[16] = {h0.x, h0.y, h0.z, h0.w, h1.x, h1.y, h1.z, h1.w,
                        h2.x, h2.y, h2.z, h2.w, h3.x, h3.y, h3.z, h3.w};
        float vprod[16];
        float run = 1.f;
#pragma unroll
        for (int j = 0; j < 16; ++j) { run *= (1.f - hv[j]); vprod[j] = run; }
        float x = run;
#pragma unroll
        for (int off = 1; off < 64; off <<= 1) {
            float o = __shfl_up(x, off, 64);
            if (lane >= off) x *= o;
        }
        float pre = __shfl_up(x, 1, 64);
        if (lane == 0) pre = 1.f;

        int p  = (int)trunc_s[row];
        int t0 = lane * 16;
        float sv[16];
#pragma unroll
        for (int j = 0; j < 16; ++j) {
            float s = pre * vprod[j];
            int t = t0 + j;
            if (t >= p) s *= __expf((float)(p - t));
            sv[j] = s;
        }
        float* Srow = out_S + (size_t)rowG * T_BINS + lane * 16;
        *(float4*)(Srow + 0)  = (float4){sv[0],  sv[1],  sv[2],  sv[3]};
        *(float4*)(Srow + 4)  = (float4){sv[4],  sv[5],  sv[6],  sv[7]};
        *(float4*)(Srow + 8)  = (float4){sv[8],  sv[9],  sv[10], sv[11]};
        *(float4*)(Srow + 12) = (float4){sv[12], sv[13], sv[14], sv[15]};
    }
}

// ---------------- fp32 fallback path (round-1 kernels), used if ws too small ----------------
#define BMf 64
#define BKf 16
#define LDSS (BMf + 4)
__global__ __launch_bounds__(256) void gemm_argmax_fp32(
    const float* __restrict__ A, const float* __restrict__ W,
    const float* __restrict__ bias, unsigned long long* __restrict__ rec)
{
    __shared__ float As[BKf][LDSS];
    __shared__ float Ws[BKf][LDSS];
    const int tid = threadIdx.x;
    const int tx = tid & 15, ty = tid >> 4;
    const int bx = blockIdx.x, by = blockIdx.y;
    const int ar = tid >> 2, ak = (tid & 3) << 2;
    const float* Arow = A + (size_t)(by * BMf + ar) * T_BINS + ak;
    const float* Wrow = W + (size_t)(bx * BMf + ar) * T_BINS + ak;
    float acc[4][4];
#pragma unroll
    for (int i = 0; i < 4; ++i)
#pragma unroll
        for (int j = 0; j < 4; ++j) acc[i][j] = 0.f;
    for (int k0 = 0; k0 < T_BINS; k0 += BKf) {
        float4 av = *(const float4*)(Arow + k0);
        float4 wvv = *(const float4*)(Wrow + k0);
        As[ak + 0][ar] = av.x; As[ak + 1][ar] = av.y; As[ak + 2][ar] = av.z; As[ak + 3][ar] = av.w;
        Ws[ak + 0][ar] = wvv.x; Ws[ak + 1][ar] = wvv.y; Ws[ak + 2][ar] = wvv.z; Ws[ak + 3][ar] = wvv.w;
        __syncthreads();
#pragma unroll
        for (int k = 0; k < BKf; ++k) {
            float4 a4 = *(const float4*)&As[k][ty * 4];
            float4 w4 = *(const float4*)&Ws[k][tx * 4];
            float aa[4] = {a4.x, a4.y, a4.z, a4.w};
            float ww[4] = {w4.x, w4.y, w4.z, w4.w};
#pragma unroll
            for (int i = 0; i < 4; ++i)
#pragma unroll
                for (int j = 0; j < 4; ++j) acc[i][j] = fmaf(aa[i], ww[j], acc[i][j]);
        }
        __syncthreads();
    }
    const int colBase = bx * BMf + tx * 4;
    float bv[4];
#pragma unroll
    for (int j = 0; j < 4; ++j) bv[j] = bias[colBase + j];
#pragma unroll
    for (int i = 0; i < 4; ++i) {
        float best = acc[i][0] + bv[0];
        int bc = colBase;
#pragma unroll
        for (int j = 1; j < 4; ++j) {
            float v = acc[i][j] + bv[j];
            if (v > best) { best = v; bc = colBase + j; }
        }
#pragma unroll
        for (int off = 8; off >= 1; off >>= 1) {
            float ov = __shfl_xor(best, off, 64);
            int oc = __shfl_xor(bc, off, 64);
            if (ov > best || (ov == best && oc < bc)) { best = ov; bc = oc; }
        }
        if (tx == 0) atomicMax(&rec[by * BMf + ty * 4 + i], pack_max(best, bc));
    }
}

__global__ __launch_bounds__(256) void finalize_kernel(
    const unsigned long long* __restrict__ rec, const float* __restrict__ labels,
    float* __restrict__ out_trunc, float* __restrict__ loss_acc)
{
    int i = blockIdx.x * 256 + threadIdx.x;
    unsigned col = ~(unsigned)(rec[i] & 0xFFFFFFFFull);
    float p = (float)col;
    out_trunc[i] = p;
    float d = p - labels[i];
    float term = d * d * (1.0f / (float)B_ROWS);
#pragma unroll
    for (int off = 32; off >= 1; off >>= 1)
        term += __shfl_down(term, off, 64);
    __shared__ float partials[4];
    int lane = threadIdx.x & 63, wv = threadIdx.x >> 6;
    if (lane == 0) partials[wv] = term;
    __syncthreads();
    if (threadIdx.x == 0)
        atomicAdd(loss_acc, partials[0] + partials[1] + partials[2] + partials[3]);
}

__global__ __launch_bounds__(256) void scan_kernel_f32(
    const float* __restrict__ H, const float* __restrict__ trunc_f,
    float* __restrict__ Sout)
{
    const int row = blockIdx.x;
    const int tid = threadIdx.x;
    const int lane = tid & 63;
    const int wv = tid >> 6;
    const float4 h = *(const float4*)(H + (size_t)row * T_BINS + tid * 4);
    float l0 = 1.f - h.x;
    float l1 = l0 * (1.f - h.y);
    float l2 = l1 * (1.f - h.z);
    float l3 = l2 * (1.f - h.w);
    float x = l3;
#pragma unroll
    for (int off = 1; off < 64; off <<= 1) {
        float o = __shfl_up(x, off, 64);
        if (lane >= off) x *= o;
    }
    float ex = __shfl_up(x, 1, 64);
    if (lane == 0) ex = 1.f;
    __shared__ float wtot[4];
    if (lane == 63) wtot[wv] = x;
    __syncthreads();
    float wpre = 1.f;
#pragma unroll
    for (int w = 0; w < 3; ++w)
        if (w < wv) wpre *= wtot[w];
    float pre = wpre * ex;
    int p = (int)trunc_f[row];
    int t0 = tid * 4;
    float sv[4] = {pre * l0, pre * l1, pre * l2, pre * l3};
#pragma unroll
    for (int j = 0; j < 4; ++j) {
        int t = t0 + j;
        if (t >= p) sv[j] *= __expf((float)(p - t));
    }
    float4 s4 = {sv[0], sv[1], sv[2], sv[3]};
    *(float4*)(Sout + (size_t)row * T_BINS + tid * 4) = s4;
}

extern "C" void kernel_launch(void* const* d_in, const int* in_sizes, int n_in,
                              void* d_out, int out_size, void* d_ws, size_t ws_size,
                              hipStream_t stream)
{
    const float* hazard = (const float*)d_in[0];   // [B, T]
    const float* labels = (const float*)d_in[1];   // [B]
    const float* W      = (const float*)d_in[2];   // [T, T]
    const float* bias   = (const float*)d_in[3];   // [T]

    float* out       = (float*)d_out;
    float* out_trunc = out;                                       // B floats
    float* out_S     = out + B_ROWS;                              // B*T floats
    float* out_loss  = out + B_ROWS + (size_t)B_ROWS * T_BINS;    // 1 float

    hipMemsetAsync(out_loss, 0, sizeof(float), stream);

    const size_t NW = (size_t)T_BINS * T_BINS;
    if (ws_size >= NW * sizeof(_Float16)) {
        _Float16* Wh = (_Float16*)d_ws;
        tof16_kernel<<<(int)(NW / 4 / 256), 256, 0, stream>>>(W, Wh, (int)(NW / 4));
        mega_kernel<<<B_ROWS / 32, 256, 0, stream>>>(
            hazard, Wh, bias, labels, out_trunc, out_S, out_loss);
    } else {
        unsigned long long* rec = (unsigned long long*)out_S;
        hipMemsetAsync(rec, 0, (size_t)B_ROWS * sizeof(unsigned long long), stream);
        dim3 ggrid(T_BINS / BMf, B_ROWS / BMf);
        gemm_argmax_fp32<<<ggrid, 256, 0, stream>>>(hazard, W, bias, rec);
        finalize_kernel<<<B_ROWS / 256, 256, 0, stream>>>(rec, labels, out_trunc, out_loss);
        scan_kernel_f32<<<B_ROWS, 256, 0, stream>>>(hazard, out_trunc, out_S);
    }
}

// Round 7
// 378.943 us; speedup vs baseline: 1.2357x; 1.2357x over previous
//
#include <hip/hip_runtime.h>

#define B_ROWS 32768
#define T_BINS 1024

typedef __attribute__((ext_vector_type(8))) _Float16 half8;
typedef __attribute__((ext_vector_type(4))) float floatx4;

__device__ __forceinline__ unsigned long long pack_max(float v, int col) {
    unsigned x = __float_as_uint(v);
    x = (x & 0x80000000u) ? ~x : (x | 0x80000000u);   // monotone float->uint
    return ((unsigned long long)x << 32) | (unsigned)(~col);  // ties -> smaller col
}

__device__ __forceinline__ void async16h(const _Float16* g, _Float16* l) {
    __builtin_amdgcn_global_load_lds(
        (const __attribute__((address_space(1))) unsigned int*)g,
        (__attribute__((address_space(3))) unsigned int*)l,
        16, 0, 0);
}

// ---------------- convert fp32 -> f16 (RNE), used for W only ----------------
__global__ __launch_bounds__(256) void tof16_kernel(
    const float* __restrict__ src, _Float16* __restrict__ dst, int n4)
{
    int idx = blockIdx.x * 256 + threadIdx.x;
    if (idx >= n4) return;
    float4 x = ((const float4*)src)[idx];
    union { _Float16 h[4]; ushort4 u; } cv;
    cv.h[0] = (_Float16)x.x;
    cv.h[1] = (_Float16)x.y;
    cv.h[2] = (_Float16)x.z;
    cv.h[3] = (_Float16)x.w;
    ((ushort4*)dst)[idx] = cv.u;
}

// ---------------- MEGA: GEMM+argmax (full row per block) + loss + scan ----------------
// M=64 rows/block (R4 geometry, best measured). Fix vs R4: LDS double-buffer with ONE
// plain __syncthreads per K-iter. Tile n+1 is staged into buf^1 while MFMA consumes
// buf (staged last iter), so the barrier's vmcnt(0) drain waits on asyncs that have
// had the whole MFMA phase to land — R4 waited on asyncs issued the same iteration.
__global__ __launch_bounds__(256, 3) void mega_kernel(
    const float* __restrict__ A, const _Float16* __restrict__ Wh,
    const float* __restrict__ bias, const float* __restrict__ labels,
    float* __restrict__ out_trunc, float* __restrict__ out_S,
    float* __restrict__ loss_acc)
{
    __shared__ _Float16 sA[2][64 * 32];     // 8 KB
    __shared__ _Float16 sW[2][256 * 32];    // 32 KB
    __shared__ unsigned long long cand[4][64];
    __shared__ float trunc_s[64];

    const int tid  = threadIdx.x;
    const int lane = tid & 63;
    const int wc   = tid >> 6;      // wave = column group 0..3
    const int by   = blockIdx.x;    // row slab 0..511

    // A staging: thread -> (row=tid>>2, kgroup=(tid&3)*8); 2xfloat4 -> half8 -> ds_write_b128
    const int arow = tid >> 2;
    const int akg  = (tid & 3) * 8;
    const float* Abase = A + (size_t)(by * 64 + arow) * T_BINS + akg;
    const int sAoff = arow * 32 + akg;

    // W staging: chunk c=r*256+tid -> wrow=c>>2, wkc=(c&3)*8; LDS base wave-uniform
    const int ko = (lane >> 4) * 8;  // k-offset of this lane's fragment

    float run_best[4][4];
    int   run_col[4][4];
#pragma unroll
    for (int i = 0; i < 4; ++i)
#pragma unroll
        for (int r = 0; r < 4; ++r) { run_best[i][r] = -3.4e38f; run_col[i][r] = 0; }

    // ---- prologue: stage tile 0 into buf 0; prefetch A regs for tile 1 ----
    {
        float4 f0 = *(const float4*)(Abase);
        float4 f1 = *(const float4*)(Abase + 4);
        half8 hv;
        hv[0] = (_Float16)f0.x; hv[1] = (_Float16)f0.y;
        hv[2] = (_Float16)f0.z; hv[3] = (_Float16)f0.w;
        hv[4] = (_Float16)f1.x; hv[5] = (_Float16)f1.y;
        hv[6] = (_Float16)f1.z; hv[7] = (_Float16)f1.w;
        *(half8*)&sA[0][sAoff] = hv;
    }
#pragma unroll
    for (int r = 0; r < 4; ++r) {
        int c = r * 256 + tid;
        int wrow = c >> 2, wkc = (c & 3) * 8;
        async16h(Wh + (size_t)wrow * T_BINS + wkc, &sW[0][(r * 256 + wc * 64) * 8]);
    }
    float4 pa0 = *(const float4*)(Abase + 32);   // A for tile 1
    float4 pa1 = *(const float4*)(Abase + 36);
    __syncthreads();   // drains W(0) asyncs (+ pa loads)

    // ---- main loop: 128 tiles (4 bx x 32 k-steps), dbuf, one barrier per iter ----
    int n = 0;
    for (int bx = 0; bx < 4; ++bx) {
        const int colbase = bx * 256 + wc * 64 + (lane & 15);
        float bj[4];
#pragma unroll
        for (int j = 0; j < 4; ++j) bj[j] = bias[colbase + j * 16];

        floatx4 acc[4][4];
#pragma unroll
        for (int i = 0; i < 4; ++i)
#pragma unroll
            for (int j = 0; j < 4; ++j) acc[i][j] = (floatx4){0.f, 0.f, 0.f, 0.f};

        for (int t = 0; t < 32; ++t, ++n) {
            const int cur = n & 1;
            const int nxt = cur ^ 1;
            const int m   = (n + 1) & 127;   // next tile (wrap at end harmless)
            const int bxn = m >> 5;
            const int k0n = (m & 31) * 32;

            // 1. prefetch A regs for tile n+2 first (max time to land before drain)
            const int kq = ((n + 2) & 31) * 32;   // A depends only on k (bx-invariant)
            float4 qa0 = *(const float4*)(Abase + kq);
            float4 qa1 = *(const float4*)(Abase + kq + 4);

            // 2. stage W(n+1) into the other buffer (consumed next iter)
#pragma unroll
            for (int r = 0; r < 4; ++r) {
                int c = r * 256 + tid;
                int wrow = c >> 2, wkc = (c & 3) * 8;
                async16h(Wh + (size_t)(bxn * 256 + wrow) * T_BINS + k0n + wkc,
                         &sW[nxt][(r * 256 + wc * 64) * 8]);
            }

            // 3. stage A(n+1) from regs into the other buffer
            {
                half8 hv;
                hv[0] = (_Float16)pa0.x; hv[1] = (_Float16)pa0.y;
                hv[2] = (_Float16)pa0.z; hv[3] = (_Float16)pa0.w;
                hv[4] = (_Float16)pa1.x; hv[5] = (_Float16)pa1.y;
                hv[6] = (_Float16)pa1.z; hv[7] = (_Float16)pa1.w;
                *(half8*)&sA[nxt][sAoff] = hv;
            }
            pa0 = qa0; pa1 = qa1;

            // 4. fragments + MFMA on current buffers (staged last iter)
            half8 ah[4], whf[4];
#pragma unroll
            for (int i = 0; i < 4; ++i)
                ah[i] = *(const half8*)&sA[cur][(i * 16 + (lane & 15)) * 32 + ko];
#pragma unroll
            for (int j = 0; j < 4; ++j)
                whf[j] = *(const half8*)&sW[cur][(wc * 64 + j * 16 + (lane & 15)) * 32 + ko];
#pragma unroll
            for (int i = 0; i < 4; ++i)
#pragma unroll
                for (int j = 0; j < 4; ++j)
                    acc[i][j] = __builtin_amdgcn_mfma_f32_16x16x32_f16(ah[i], whf[j], acc[i][j], 0, 0, 0);

            // 5. single barrier: waits W(n+1)/A(n+1) staging (issued ~full iter ago
            //    or overlapped with 16 MFMAs) and guards the buffer swap.
            __syncthreads();
        }

        // fold this bx's acc into the running argmax (cols strictly increase)
#pragma unroll
        for (int i = 0; i < 4; ++i)
#pragma unroll
            for (int r = 0; r < 4; ++r)
#pragma unroll
                for (int j = 0; j < 4; ++j) {
                    float v = acc[i][j][r] + bj[j];
                    if (v > run_best[i][r]) { run_best[i][r] = v; run_col[i][r] = colbase + j * 16; }
                }
    }

    // 16-lane (column-lane) reduce; lanes {0,16,32,48} publish per-row candidates
#pragma unroll
    for (int i = 0; i < 4; ++i)
#pragma unroll
        for (int r = 0; r < 4; ++r) {
            float best = run_best[i][r];
            int   bc   = run_col[i][r];
#pragma unroll
            for (int off = 8; off >= 1; off >>= 1) {
                float ov = __shfl_xor(best, off, 64);
                int   oc = __shfl_xor(bc, off, 64);
                if (ov > best || (ov == best && oc < bc)) { best = ov; bc = oc; }
            }
            if ((lane & 15) == 0)
                cand[wc][i * 16 + (lane >> 4) * 4 + r] = pack_max(best, bc);
        }
    __syncthreads();

    // wave 0: combine 4 col-group candidates per row, write trunc_pos + loss
    if (tid < 64) {
        unsigned long long m01 = cand[0][tid] > cand[1][tid] ? cand[0][tid] : cand[1][tid];
        unsigned long long m23 = cand[2][tid] > cand[3][tid] ? cand[2][tid] : cand[3][tid];
        unsigned long long mm = m01 > m23 ? m01 : m23;
        unsigned col = ~(unsigned)mm;
        float p = (float)col;
        int rowG = by * 64 + tid;
        out_trunc[rowG] = p;
        trunc_s[tid] = p;
        float d = p - labels[rowG];
        float term = d * d * (1.0f / (float)B_ROWS);
#pragma unroll
        for (int off = 32; off >= 1; off >>= 1)
            term += __shfl_down(term, off, 64);
        if (tid == 0) atomicAdd(loss_acc, term);
    }
    __syncthreads();

    // scan phase: wave wc handles rows wc*16 .. wc*16+15; lane covers 16 elements
    for (int rr = 0; rr < 16; ++rr) {
        int row  = wc * 16 + rr;
        int rowG = by * 64 + row;
        const float* Hrow = A + (size_t)rowG * T_BINS + lane * 16;
        float4 h0 = *(const float4*)(Hrow + 0);
        float4 h1 = *(const float4*)(Hrow + 4);
        float4 h2 = *(const float4*)(Hrow + 8);
        float4 h3 = *(const float4*)(Hrow + 12);
        float hv[16] = {h0.x, h0.y, h0.z, h0.w, h1.x, h1.y, h1.z, h1.w,
                        h2.x, h2.y, h2.z, h2.w, h3.x, h3.y, h3.z, h3.w};
        float vprod[16];
        float run = 1.f;
#pragma unroll
        for (int j = 0; j < 16; ++j) { run *= (1.f - hv[j]); vprod[j] = run; }
        float x = run;
#pragma unroll
        for (int off = 1; off < 64; off <<= 1) {
            float o = __shfl_up(x, off, 64);
            if (lane >= off) x *= o;
        }
        float pre = __shfl_up(x, 1, 64);
        if (lane == 0) pre = 1.f;

        int p  = (int)trunc_s[row];
        int t0 = lane * 16;
        float sv[16];
#pragma unroll
        for (int j = 0; j < 16; ++j) {
            float s = pre * vprod[j];
            int t = t0 + j;
            if (t >= p) s *= __expf((float)(p - t));
            sv[j] = s;
        }
        float* Srow = out_S + (size_t)rowG * T_BINS + lane * 16;
        *(float4*)(Srow + 0)  = (float4){sv[0],  sv[1],  sv[2],  sv[3]};
        *(float4*)(Srow + 4)  = (float4){sv[4],  sv[5],  sv[6],  sv[7]};
        *(float4*)(Srow + 8)  = (float4){sv[8],  sv[9],  sv[10], sv[11]};
        *(float4*)(Srow + 12) = (float4){sv[12], sv[13], sv[14], sv[15]};
    }
}

// ---------------- fp32 fallback path (round-1 kernels), used if ws too small ----------------
#define BMf 64
#define BKf 16
#define LDSS (BMf + 4)
__global__ __launch_bounds__(256) void gemm_argmax_fp32(
    const float* __restrict__ A, const float* __restrict__ W,
    const float* __restrict__ bias, unsigned long long* __restrict__ rec)
{
    __shared__ float As[BKf][LDSS];
    __shared__ float Ws[BKf][LDSS];
    const int tid = threadIdx.x;
    const int tx = tid & 15, ty = tid >> 4;
    const int bx = blockIdx.x, by = blockIdx.y;
    const int ar = tid >> 2, ak = (tid & 3) << 2;
    const float* Arow = A + (size_t)(by * BMf + ar) * T_BINS + ak;
    const float* Wrow = W + (size_t)(bx * BMf + ar) * T_BINS + ak;
    float acc[4][4];
#pragma unroll
    for (int i = 0; i < 4; ++i)
#pragma unroll
        for (int j = 0; j < 4; ++j) acc[i][j] = 0.f;
    for (int k0 = 0; k0 < T_BINS; k0 += BKf) {
        float4 av = *(const float4*)(Arow + k0);
        float4 wvv = *(const float4*)(Wrow + k0);
        As[ak + 0][ar] = av.x; As[ak + 1][ar] = av.y; As[ak + 2][ar] = av.z; As[ak + 3][ar] = av.w;
        Ws[ak + 0][ar] = wvv.x; Ws[ak + 1][ar] = wvv.y; Ws[ak + 2][ar] = wvv.z; Ws[ak + 3][ar] = wvv.w;
        __syncthreads();
#pragma unroll
        for (int k = 0; k < BKf; ++k) {
            float4 a4 = *(const float4*)&As[k][ty * 4];
            float4 w4 = *(const float4*)&Ws[k][tx * 4];
            float aa[4] = {a4.x, a4.y, a4.z, a4.w};
            float ww[4] = {w4.x, w4.y, w4.z, w4.w};
#pragma unroll
            for (int i = 0; i < 4; ++i)
#pragma unroll
                for (int j = 0; j < 4; ++j) acc[i][j] = fmaf(aa[i], ww[j], acc[i][j]);
        }
        __syncthreads();
    }
    const int colBase = bx * BMf + tx * 4;
    float bv[4];
#pragma unroll
    for (int j = 0; j < 4; ++j) bv[j] = bias[colBase + j];
#pragma unroll
    for (int i = 0; i < 4; ++i) {
        float best = acc[i][0] + bv[0];
        int bc = colBase;
#pragma unroll
        for (int j = 1; j < 4; ++j) {
            float v = acc[i][j] + bv[j];
            if (v > best) { best = v; bc = colBase + j; }
        }
#pragma unroll
        for (int off = 8; off >= 1; off >>= 1) {
            float ov = __shfl_xor(best, off, 64);
            int oc = __shfl_xor(bc, off, 64);
            if (ov > best || (ov == best && oc < bc)) { best = ov; bc = oc; }
        }
        if (tx == 0) atomicMax(&rec[by * BMf + ty * 4 + i], pack_max(best, bc));
    }
}

__global__ __launch_bounds__(256) void finalize_kernel(
    const unsigned long long* __restrict__ rec, const float* __restrict__ labels,
    float* __restrict__ out_trunc, float* __restrict__ loss_acc)
{
    int i = blockIdx.x * 256 + threadIdx.x;
    unsigned col = ~(unsigned)(rec[i] & 0xFFFFFFFFull);
    float p = (float)col;
    out_trunc[i] = p;
    float d = p - labels[i];
    float term = d * d * (1.0f / (float)B_ROWS);
#pragma unroll
    for (int off = 32; off >= 1; off >>= 1)
        term += __shfl_down(term, off, 64);
    __shared__ float partials[4];
    int lane = threadIdx.x & 63, wv = threadIdx.x >> 6;
    if (lane == 0) partials[wv] = term;
    __syncthreads();
    if (threadIdx.x == 0)
        atomicAdd(loss_acc, partials[0] + partials[1] + partials[2] + partials[3]);
}

__global__ __launch_bounds__(256) void scan_kernel_f32(
    const float* __restrict__ H, const float* __restrict__ trunc_f,
    float* __restrict__ Sout)
{
    const int row = blockIdx.x;
    const int tid = threadIdx.x;
    const int lane = tid & 63;
    const int wv = tid >> 6;
    const float4 h = *(const float4*)(H + (size_t)row * T_BINS + tid * 4);
    float l0 = 1.f - h.x;
    float l1 = l0 * (1.f - h.y);
    float l2 = l1 * (1.f - h.z);
    float l3 = l2 * (1.f - h.w);
    float x = l3;
#pragma unroll
    for (int off = 1; off < 64; off <<= 1) {
        float o = __shfl_up(x, off, 64);
        if (lane >= off) x *= o;
    }
    float ex = __shfl_up(x, 1, 64);
    if (lane == 0) ex = 1.f;
    __shared__ float wtot[4];
    if (lane == 63) wtot[wv] = x;
    __syncthreads();
    float wpre = 1.f;
#pragma unroll
    for (int w = 0; w < 3; ++w)
        if (w < wv) wpre *= wtot[w];
    float pre = wpre * ex;
    int p = (int)trunc_f[row];
    int t0 = tid * 4;
    float sv[4] = {pre * l0, pre * l1, pre * l2, pre * l3};
#pragma unroll
    for (int j = 0; j < 4; ++j) {
        int t = t0 + j;
        if (t >= p) sv[j] *= __expf((float)(p - t));
    }
    float4 s4 = {sv[0], sv[1], sv[2], sv[3]};
    *(float4*)(Sout + (size_t)row * T_BINS + tid * 4) = s4;
}

extern "C" void kernel_launch(void* const* d_in, const int* in_sizes, int n_in,
                              void* d_out, int out_size, void* d_ws, size_t ws_size,
                              hipStream_t stream)
{
    const float* hazard = (const float*)d_in[0];   // [B, T]
    const float* labels = (const float*)d_in[1];   // [B]
    const float* W      = (const float*)d_in[2];   // [T, T]
    const float* bias   = (const float*)d_in[3];   // [T]

    float* out       = (float*)d_out;
    float* out_trunc = out;                                       // B floats
    float* out_S     = out + B_ROWS;                              // B*T floats
    float* out_loss  = out + B_ROWS + (size_t)B_ROWS * T_BINS;    // 1 float

    hipMemsetAsync(out_loss, 0, sizeof(float), stream);

    const size_t NW = (size_t)T_BINS * T_BINS;
    if (ws_size >= NW * sizeof(_Float16)) {
        _Float16* Wh = (_Float16*)d_ws;
        tof16_kernel<<<(int)(NW / 4 / 256), 256, 0, stream>>>(W, Wh, (int)(NW / 4));
        mega_kernel<<<B_ROWS / 64, 256, 0, stream>>>(
            hazard, Wh, bias, labels, out_trunc, out_S, out_loss);
    } else {
        unsigned long long* rec = (unsigned long long*)out_S;
        hipMemsetAsync(rec, 0, (size_t)B_ROWS * sizeof(unsigned long long), stream);
        dim3 ggrid(T_BINS / BMf, B_ROWS / BMf);
        gemm_argmax_fp32<<<ggrid, 256, 0, stream>>>(hazard, W, bias, rec);
        finalize_kernel<<<B_ROWS / 256, 256, 0, stream>>>(rec, labels, out_trunc, out_loss);
        scan_kernel_f32<<<B_ROWS, 256, 0, stream>>>(hazard, out_trunc, out_S);
    }
}